// Round 1
// baseline (1389.331 us; speedup 1.0000x reference)
//
#include <hip/hip_runtime.h>
#include <hip/hip_bf16.h>
#include <cstddef>

// Problem constants (fixed by the reference)
constexpr int T_ = 512;
constexpr int B_ = 8;
constexpr int H_ = 256;
constexpr int V_ = 32000;
constexpr int L_ = 3;
constexpr int M_ = T_ * B_;   // 4096 rows in all GEMMs

// ---------------------------------------------------------------------------
// Embed: h[t,b,:] = token_emb[tokens[t,b],:] + pos_emb[t,:]
// One float4 per thread. Total T*B*H/4 = 262144 float4s.
// ---------------------------------------------------------------------------
__global__ __launch_bounds__(256) void embed_kernel(
    const int* __restrict__ tokens, const float* __restrict__ temb,
    const float* __restrict__ pemb, float* __restrict__ h)
{
    const int idx = blockIdx.x * 256 + threadIdx.x;      // 0 .. T*B*H/4-1
    const int h4 = idx & (H_ / 4 - 1);                   // 0..63
    const int tb = idx >> 6;                             // 0..4095
    const int b  = tb & (B_ - 1);
    const int t  = tb >> 3;
    const int tok = tokens[t * B_ + b];
    const float4 e = *(const float4*)&temb[(size_t)tok * H_ + h4 * 4];
    const float4 p = *(const float4*)&pemb[(size_t)t * H_ + h4 * 4];
    float4 r;
    r.x = e.x + p.x; r.y = e.y + p.y; r.z = e.z + p.z; r.w = e.w + p.w;
    *(float4*)&h[(size_t)idx * 4] = r;
}

// ---------------------------------------------------------------------------
// Leaky scan + spike: mem[t] = beta*mem[t-1] + cur[t]; spk = (mem > 1) ? 1 : 0
// 2048 independent chains (b,h). Coalesced loads (consecutive tid = consecutive
// address). 32 blocks x 64 threads to spread across CUs.
// ---------------------------------------------------------------------------
__global__ __launch_bounds__(64) void scan_spike_kernel(
    const float* __restrict__ cur, const float* __restrict__ beta_l,
    float* __restrict__ spk)
{
    const int tid = blockIdx.x * 64 + threadIdx.x;       // 0..2047
    const int hh = tid & (H_ - 1);
    const int b  = tid >> 8;
    const float bt = beta_l[hh];
    const float* p = cur + (size_t)b * H_ + hh;
    float* q = spk + (size_t)b * H_ + hh;
    float mem = 0.0f;
    constexpr size_t stride = (size_t)B_ * H_;
    #pragma unroll 8
    for (int t = 0; t < T_; ++t) {
        mem = fmaf(bt, mem, p[(size_t)t * stride]);
        q[(size_t)t * stride] = (mem > 1.0f) ? 1.0f : 0.0f;
    }
}

// ---------------------------------------------------------------------------
// Tiled fp32 GEMM: C[M,N] = act(A[M,K] @ B[K,N] + bias[N])
// 256 threads; BK=16; each thread computes TM x TN. All dims divide evenly
// for this problem (M=4096, N in {256, 32000}, K=256) -> no bounds checks.
// ---------------------------------------------------------------------------
template <int BM, int BN, int TM, int TN, int RELU>
__global__ __launch_bounds__(256) void gemm_f32(
    const float* __restrict__ A, const float* __restrict__ B,
    const float* __restrict__ bias, float* __restrict__ C,
    int M, int N, int K)
{
    constexpr int BK = 16;
    constexpr int TX = BN / TN;   // threads along n (=16)
    constexpr int TY = BM / TM;   // threads along m (=16)
    static_assert(TX * TY == 256, "thread layout");
    constexpr int AL = BM * BK / 1024;   // float4 A-loads per thread
    constexpr int BL = BN * BK / 1024;   // float4 B-loads per thread

    __shared__ float As[BK][BM + 4];
    __shared__ float Bs[BK][BN + 4];

    const int tid = threadIdx.x;
    const int tx = tid % TX, ty = tid / TX;
    const int m0 = blockIdx.y * BM, n0 = blockIdx.x * BN;

    // A-load mapping: k-quad + row
    const int a_c4 = tid & 3;        // which float4 along K
    const int a_m  = tid >> 2;       // 0..63
    // B-load mapping: n-quad + k-row
    const int b_n4 = tid % (BN / 4);
    const int b_k  = tid / (BN / 4); // 0..(1024/BN*BK/?) rows, stride 1024/BN

    float acc[TM][TN] = {};

    for (int k0 = 0; k0 < K; k0 += BK) {
        float4 av[AL], bv[BL];
        #pragma unroll
        for (int i = 0; i < AL; ++i)
            av[i] = *(const float4*)&A[(size_t)(m0 + a_m + 64 * i) * K + k0 + a_c4 * 4];
        #pragma unroll
        for (int i = 0; i < BL; ++i)
            bv[i] = *(const float4*)&B[(size_t)(k0 + b_k + i * (1024 / BN)) * N + n0 + b_n4 * 4];

        if (k0) __syncthreads();   // previous tile fully consumed
        #pragma unroll
        for (int i = 0; i < AL; ++i) {
            As[a_c4 * 4 + 0][a_m + 64 * i] = av[i].x;
            As[a_c4 * 4 + 1][a_m + 64 * i] = av[i].y;
            As[a_c4 * 4 + 2][a_m + 64 * i] = av[i].z;
            As[a_c4 * 4 + 3][a_m + 64 * i] = av[i].w;
        }
        #pragma unroll
        for (int i = 0; i < BL; ++i)
            *(float4*)&Bs[b_k + i * (1024 / BN)][b_n4 * 4] = bv[i];
        __syncthreads();

        #pragma unroll
        for (int k = 0; k < BK; ++k) {
            float a[TM], b[TN];
            #pragma unroll
            for (int i = 0; i < TM; i += 4)
                *(float4*)&a[i] = *(const float4*)&As[k][ty * TM + i];
            #pragma unroll
            for (int j = 0; j < TN; j += 4)
                *(float4*)&b[j] = *(const float4*)&Bs[k][tx * TN + j];
            #pragma unroll
            for (int i = 0; i < TM; ++i)
                #pragma unroll
                for (int j = 0; j < TN; ++j)
                    acc[i][j] = fmaf(a[i], b[j], acc[i][j]);
        }
    }

    // Epilogue: bias (+ optional ReLU), float4 stores
    #pragma unroll
    for (int i = 0; i < TM; ++i) {
        const size_t row = (size_t)(m0 + ty * TM + i);
        #pragma unroll
        for (int j = 0; j < TN; j += 4) {
            const int col = n0 + tx * TN + j;
            float4 r;
            r.x = acc[i][j + 0] + bias[col + 0];
            r.y = acc[i][j + 1] + bias[col + 1];
            r.z = acc[i][j + 2] + bias[col + 2];
            r.w = acc[i][j + 3] + bias[col + 3];
            if (RELU) {
                r.x = fmaxf(r.x, 0.0f); r.y = fmaxf(r.y, 0.0f);
                r.z = fmaxf(r.z, 0.0f); r.w = fmaxf(r.w, 0.0f);
            }
            *(float4*)&C[row * (size_t)N + col] = r;
        }
    }
}

// ---------------------------------------------------------------------------
extern "C" void kernel_launch(void* const* d_in, const int* in_sizes, int n_in,
                              void* d_out, int out_size, void* d_ws, size_t ws_size,
                              hipStream_t stream)
{
    const int*   tokens = (const int*)  d_in[0];
    const float* temb   = (const float*)d_in[1];
    const float* pemb   = (const float*)d_in[2];
    const float* Wq     = (const float*)d_in[3];
    const float* bq     = (const float*)d_in[4];
    const float* beta   = (const float*)d_in[5];
    const float* Wfc    = (const float*)d_in[6];
    const float* bfc    = (const float*)d_in[7];
    const float* Wout   = (const float*)d_in[8];
    const float* bout   = (const float*)d_in[9];
    float* out = (float*)d_out;

    // Workspace: three (T*B, H) fp32 buffers = 3 * 4 MiB
    float* h   = (float*)d_ws;
    float* cur = h   + (size_t)M_ * H_;
    float* spk = cur + (size_t)M_ * H_;

    // 1) embed
    embed_kernel<<<(M_ * H_ / 4) / 256, 256, 0, stream>>>(tokens, temb, pemb, h);

    // 2) layers
    for (int l = 0; l < L_; ++l) {
        gemm_f32<64, 64, 4, 4, 0><<<dim3(H_ / 64, M_ / 64), 256, 0, stream>>>(
            h, Wq + (size_t)l * H_ * H_, bq + (size_t)l * H_, cur, M_, H_, H_);
        scan_spike_kernel<<<(B_ * H_) / 64, 64, 0, stream>>>(
            cur, beta + (size_t)l * H_, spk);
        gemm_f32<64, 64, 4, 4, 1><<<dim3(H_ / 64, M_ / 64), 256, 0, stream>>>(
            spk, Wfc + (size_t)l * H_ * H_, bfc + (size_t)l * H_, h, M_, H_, H_);
    }

    // 3) output projection: (4096 x 256) @ (256 x 32000) + bout
    gemm_f32<128, 128, 8, 8, 0><<<dim3(V_ / 128, M_ / 128), 256, 0, stream>>>(
        h, Wout, bout, out, M_, V_, H_);
}

// Round 2
// 889.517 us; speedup vs baseline: 1.5619x; 1.5619x over previous
//
#include <hip/hip_runtime.h>
#include <hip/hip_bf16.h>
#include <cstddef>

// Problem constants (fixed by the reference)
constexpr int T_ = 512;
constexpr int B_ = 8;
constexpr int H_ = 256;
constexpr int V_ = 32000;
constexpr int L_ = 3;
constexpr int M_ = T_ * B_;   // 4096 rows in all GEMMs

typedef __attribute__((ext_vector_type(8))) short short8;
typedef __attribute__((ext_vector_type(4))) float floatx4;

// fp32 -> bf16 round-to-nearest-even
__device__ __forceinline__ unsigned short f2bf(float f) {
    unsigned u = __float_as_uint(f);
    u += 0x7fffu + ((u >> 16) & 1u);
    return (unsigned short)(u >> 16);
}

// async global->LDS, 16B per lane; LDS dest = wave-uniform base + lane*16
__device__ __forceinline__ void gl_lds16(const void* g, void* l) {
    __builtin_amdgcn_global_load_lds((__attribute__((address_space(1))) void*)g,
                                     (__attribute__((address_space(3))) void*)l,
                                     16, 0, 0);
}

// ---------------------------------------------------------------------------
// Embed: h[t,b,:] = token_emb[tokens[t,b],:] + pos_emb[t,:]
// ---------------------------------------------------------------------------
__global__ __launch_bounds__(256) void embed_kernel(
    const int* __restrict__ tokens, const float* __restrict__ temb,
    const float* __restrict__ pemb, float* __restrict__ h)
{
    const int idx = blockIdx.x * 256 + threadIdx.x;      // 0 .. T*B*H/4-1
    const int h4 = idx & (H_ / 4 - 1);                   // 0..63
    const int tb = idx >> 6;                             // 0..4095
    const int b  = tb & (B_ - 1);
    const int t  = tb >> 3;
    const int tok = tokens[t * B_ + b];
    const float4 e = *(const float4*)&temb[(size_t)tok * H_ + h4 * 4];
    const float4 p = *(const float4*)&pemb[(size_t)t * H_ + h4 * 4];
    float4 r;
    r.x = e.x + p.x; r.y = e.y + p.y; r.z = e.z + p.z; r.w = e.w + p.w;
    *(float4*)&h[(size_t)idx * 4] = r;
}

// ---------------------------------------------------------------------------
// LDS-staged leaky scan + spike. One block per batch b, 256 threads = 256 h
// chains. Double-buffered 32-t chunks in LDS hide global latency. The fmaf
// recurrence order is IDENTICAL to the R1 kernel (bit-exact results).
// ---------------------------------------------------------------------------
__global__ __launch_bounds__(256) void scan_spike_lds(
    const float* __restrict__ cur, const float* __restrict__ beta_l,
    float* __restrict__ spk)
{
    __shared__ float buf[2][32][256];                     // 64 KiB
    const int b = blockIdx.x;                             // 0..7
    const int tid = threadIdx.x;                          // h chain
    const float bt = beta_l[tid];
    const float* base = cur + (size_t)b * H_;
    float* qb = spk + (size_t)b * H_ + tid;
    constexpr int CH = 32;
    constexpr int NC = T_ / CH;                           // 16
    constexpr size_t TS = (size_t)B_ * H_;                // 2048

    float4 regs[8];
    // stage chunk 0
    #pragma unroll
    for (int i = 0; i < 8; ++i) {
        const int fi = tid + 256 * i, r = fi >> 6, x = fi & 63;
        regs[i] = *(const float4*)&base[(size_t)r * TS + x * 4];
    }
    #pragma unroll
    for (int i = 0; i < 8; ++i) {
        const int fi = tid + 256 * i, r = fi >> 6, x = fi & 63;
        *(float4*)&buf[0][r][x * 4] = regs[i];
    }

    float mem = 0.0f;
    for (int c = 0; c < NC; ++c) {
        __syncthreads();
        if (c + 1 < NC) {
            #pragma unroll
            for (int i = 0; i < 8; ++i) {
                const int fi = tid + 256 * i, r = fi >> 6, x = fi & 63;
                regs[i] = *(const float4*)&base[(size_t)((c + 1) * CH + r) * TS + x * 4];
            }
        }
        const int p = c & 1;
        #pragma unroll
        for (int tt = 0; tt < CH; ++tt) {
            mem = fmaf(bt, mem, buf[p][tt][tid]);
            qb[(size_t)(c * CH + tt) * TS] = (mem > 1.0f) ? 1.0f : 0.0f;
        }
        if (c + 1 < NC) {
            #pragma unroll
            for (int i = 0; i < 8; ++i) {
                const int fi = tid + 256 * i, r = fi >> 6, x = fi & 63;
                *(float4*)&buf[(c + 1) & 1][r][x * 4] = regs[i];
            }
        }
    }
}

// ---------------------------------------------------------------------------
// Tiled fp32 GEMM (layer path, unchanged from the passing R1 kernel)
// ---------------------------------------------------------------------------
template <int BM, int BN, int TM, int TN, int RELU>
__global__ __launch_bounds__(256) void gemm_f32(
    const float* __restrict__ A, const float* __restrict__ B,
    const float* __restrict__ bias, float* __restrict__ C,
    int M, int N, int K)
{
    constexpr int BK = 16;
    constexpr int TX = BN / TN;
    constexpr int TY = BM / TM;
    static_assert(TX * TY == 256, "thread layout");
    constexpr int AL = BM * BK / 1024;
    constexpr int BL = BN * BK / 1024;

    __shared__ float As[BK][BM + 4];
    __shared__ float Bs[BK][BN + 4];

    const int tid = threadIdx.x;
    const int tx = tid % TX, ty = tid / TX;
    const int m0 = blockIdx.y * BM, n0 = blockIdx.x * BN;

    const int a_c4 = tid & 3;
    const int a_m  = tid >> 2;
    const int b_n4 = tid % (BN / 4);
    const int b_k  = tid / (BN / 4);

    float acc[TM][TN] = {};

    for (int k0 = 0; k0 < K; k0 += BK) {
        float4 av[AL], bv[BL];
        #pragma unroll
        for (int i = 0; i < AL; ++i)
            av[i] = *(const float4*)&A[(size_t)(m0 + a_m + 64 * i) * K + k0 + a_c4 * 4];
        #pragma unroll
        for (int i = 0; i < BL; ++i)
            bv[i] = *(const float4*)&B[(size_t)(k0 + b_k + i * (1024 / BN)) * N + n0 + b_n4 * 4];

        if (k0) __syncthreads();
        #pragma unroll
        for (int i = 0; i < AL; ++i) {
            As[a_c4 * 4 + 0][a_m + 64 * i] = av[i].x;
            As[a_c4 * 4 + 1][a_m + 64 * i] = av[i].y;
            As[a_c4 * 4 + 2][a_m + 64 * i] = av[i].z;
            As[a_c4 * 4 + 3][a_m + 64 * i] = av[i].w;
        }
        #pragma unroll
        for (int i = 0; i < BL; ++i)
            *(float4*)&Bs[b_k + i * (1024 / BN)][b_n4 * 4] = bv[i];
        __syncthreads();

        #pragma unroll
        for (int k = 0; k < BK; ++k) {
            float a[TM], b[TN];
            #pragma unroll
            for (int i = 0; i < TM; i += 4)
                *(float4*)&a[i] = *(const float4*)&As[k][ty * TM + i];
            #pragma unroll
            for (int j = 0; j < TN; j += 4)
                *(float4*)&b[j] = *(const float4*)&Bs[k][tx * TN + j];
            #pragma unroll
            for (int i = 0; i < TM; ++i)
                #pragma unroll
                for (int j = 0; j < TN; ++j)
                    acc[i][j] = fmaf(a[i], b[j], acc[i][j]);
        }
    }

    #pragma unroll
    for (int i = 0; i < TM; ++i) {
        const size_t row = (size_t)(m0 + ty * TM + i);
        #pragma unroll
        for (int j = 0; j < TN; j += 4) {
            const int col = n0 + tx * TN + j;
            float4 r;
            r.x = acc[i][j + 0] + bias[col + 0];
            r.y = acc[i][j + 1] + bias[col + 1];
            r.z = acc[i][j + 2] + bias[col + 2];
            r.w = acc[i][j + 3] + bias[col + 3];
            if (RELU) {
                r.x = fmaxf(r.x, 0.0f); r.y = fmaxf(r.y, 0.0f);
                r.z = fmaxf(r.z, 0.0f); r.w = fmaxf(r.w, 0.0f);
            }
            *(float4*)&C[row * (size_t)N + col] = r;
        }
    }
}

// ---------------------------------------------------------------------------
// Wout [K=256][V] fp32  ->  Wt [V][K=256] bf16 (transpose + cast, LDS tile)
// ---------------------------------------------------------------------------
__global__ __launch_bounds__(256) void transpose_cast_kernel(
    const float* __restrict__ W, unsigned short* __restrict__ Wt)
{
    __shared__ float t[64][65];
    const int n0 = blockIdx.x * 64;      // 0..499
    const int k0 = blockIdx.y * 64;      // 0..3
    const int x = threadIdx.x & 63, y = threadIdx.x >> 6;   // y: 0..3
    #pragma unroll
    for (int i = 0; i < 16; ++i)
        t[y + 4 * i][x] = W[(size_t)(k0 + y + 4 * i) * V_ + n0 + x];
    __syncthreads();
    #pragma unroll
    for (int i = 0; i < 16; ++i)
        Wt[(size_t)(n0 + y + 4 * i) * H_ + k0 + x] = f2bf(t[x][y + 4 * i]);
}

// ---------------------------------------------------------------------------
// h fp32 -> bf16 cast
// ---------------------------------------------------------------------------
__global__ __launch_bounds__(256) void cast_h_kernel(
    const float* __restrict__ h, unsigned short* __restrict__ hb)
{
    const int i = blockIdx.x * 256 + threadIdx.x;        // per float4
    const float4 v = *(const float4*)&h[(size_t)i * 4];
    ushort4 r;
    r.x = f2bf(v.x); r.y = f2bf(v.y); r.z = f2bf(v.z); r.w = f2bf(v.w);
    *(ushort4*)&hb[(size_t)i * 4] = r;
}

// ---------------------------------------------------------------------------
// bf16 MFMA GEMM: C[M,N] = A[M,K]bf16 @ Bt[N,K]bf16^T + bias, fp32 out.
// 128x128 tile, BK=32, 4 waves (2x2), each wave 64x64 via 4x4 16x16x32 MFMAs.
// Staging via global_load_lds width-16 into k-octet-major LDS [4][128][8]
// (conflict-free ds_read_b128 fragments).
// ---------------------------------------------------------------------------
__global__ __launch_bounds__(256) void gemm_mfma_bf16(
    const unsigned short* __restrict__ A,   // [M][K]
    const unsigned short* __restrict__ Bt,  // [N][K]
    const float* __restrict__ bias,         // [N]
    float* __restrict__ C, int M, int N, int K)
{
    constexpr int BM = 128, BN = 128, BK = 32;
    __shared__ __align__(16) short lA[4][BM][8];   // 8 KiB
    __shared__ __align__(16) short lB[4][BN][8];   // 8 KiB

    const int tid = threadIdx.x;
    const int lane = tid & 63, wave = tid >> 6;
    const int wm = wave >> 1, wn = wave & 1;
    const int l15 = lane & 15, quad = lane >> 4;
    const int m0 = blockIdx.x * BM;        // x = m (fast) -> B-tile L2 reuse
    const int n0 = blockIdx.y * BN;

    floatx4 acc[4][4] = {};

    for (int k0 = 0; k0 < K; k0 += BK) {
        #pragma unroll
        for (int j = 0; j < 2; ++j) {
            const int base = wave * 128 + j * 64;        // chunk base (16B units)
            const int ch = base + lane;
            const int row = ch & 127, c4 = ch >> 7;
            gl_lds16(A  + (size_t)(m0 + row) * K + k0 + c4 * 8,
                     (short*)lA + (size_t)base * 8);
            gl_lds16(Bt + (size_t)(n0 + row) * K + k0 + c4 * 8,
                     (short*)lB + (size_t)base * 8);
        }
        __syncthreads();

        short8 af[4], bf[4];
        #pragma unroll
        for (int f = 0; f < 4; ++f) {
            af[f] = *(const short8*)&lA[quad][wm * 64 + f * 16 + l15][0];
            bf[f] = *(const short8*)&lB[quad][wn * 64 + f * 16 + l15][0];
        }
        #pragma unroll
        for (int i = 0; i < 4; ++i)
            #pragma unroll
            for (int j2 = 0; j2 < 4; ++j2)
                acc[i][j2] = __builtin_amdgcn_mfma_f32_16x16x32_bf16(
                    af[i], bf[j2], acc[i][j2], 0, 0, 0);
        __syncthreads();
    }

    // Epilogue: D layout col=lane&15, row=quad*4+reg (m89/m91-verified)
    #pragma unroll
    for (int j2 = 0; j2 < 4; ++j2) {
        const int col = n0 + wn * 64 + j2 * 16 + l15;
        const float bv = bias[col];
        #pragma unroll
        for (int i = 0; i < 4; ++i) {
            const int rbase = m0 + wm * 64 + i * 16 + quad * 4;
            #pragma unroll
            for (int r = 0; r < 4; ++r)
                C[(size_t)(rbase + r) * N + col] = acc[i][j2][r] + bv;
        }
    }
}

// ---------------------------------------------------------------------------
extern "C" void kernel_launch(void* const* d_in, const int* in_sizes, int n_in,
                              void* d_out, int out_size, void* d_ws, size_t ws_size,
                              hipStream_t stream)
{
    const int*   tokens = (const int*)  d_in[0];
    const float* temb   = (const float*)d_in[1];
    const float* pemb   = (const float*)d_in[2];
    const float* Wq     = (const float*)d_in[3];
    const float* bq     = (const float*)d_in[4];
    const float* beta   = (const float*)d_in[5];
    const float* Wfc    = (const float*)d_in[6];
    const float* bfc    = (const float*)d_in[7];
    const float* Wout   = (const float*)d_in[8];
    const float* bout   = (const float*)d_in[9];
    float* out = (float*)d_out;

    // Workspace: h, cur, spk (fp32, 4 MiB each) + h_bf (2 MiB) + Wt (16 MiB)
    float* h   = (float*)d_ws;
    float* cur = h   + (size_t)M_ * H_;
    float* spk = cur + (size_t)M_ * H_;
    unsigned short* h_bf = (unsigned short*)(spk + (size_t)M_ * H_);
    unsigned short* Wt   = h_bf + (size_t)M_ * H_;

    // Wout transpose+cast (independent of layer pipeline)
    transpose_cast_kernel<<<dim3(V_ / 64, H_ / 64), 256, 0, stream>>>(Wout, Wt);

    // 1) embed
    embed_kernel<<<(M_ * H_ / 4) / 256, 256, 0, stream>>>(tokens, temb, pemb, h);

    // 2) layers (fp32 path, bit-identical to R1)
    for (int l = 0; l < L_; ++l) {
        gemm_f32<64, 64, 4, 4, 0><<<dim3(H_ / 64, M_ / 64), 256, 0, stream>>>(
            h, Wq + (size_t)l * H_ * H_, bq + (size_t)l * H_, cur, M_, H_, H_);
        scan_spike_lds<<<B_, 256, 0, stream>>>(cur, beta + (size_t)l * H_, spk);
        gemm_f32<64, 64, 4, 4, 1><<<dim3(H_ / 64, M_ / 64), 256, 0, stream>>>(
            spk, Wfc + (size_t)l * H_ * H_, bfc + (size_t)l * H_, h, M_, H_, H_);
    }

    // 3) cast h -> bf16, then bf16 MFMA output projection
    cast_h_kernel<<<(M_ * H_ / 4) / 256, 256, 0, stream>>>(h, h_bf);
    gemm_mfma_bf16<<<dim3(M_ / 128, V_ / 128), 256, 0, stream>>>(
        h_bf, Wt, bout, out, M_, V_, H_);
}

// Round 3
// 751.775 us; speedup vs baseline: 1.8481x; 1.1832x over previous
//
#include <hip/hip_runtime.h>
#include <hip/hip_bf16.h>
#include <cstddef>

// Problem constants (fixed by the reference)
constexpr int T_ = 512;
constexpr int B_ = 8;
constexpr int H_ = 256;
constexpr int V_ = 32000;
constexpr int L_ = 3;
constexpr int M_ = T_ * B_;   // 4096 rows in all GEMMs

typedef __attribute__((ext_vector_type(8))) short short8;
typedef __attribute__((ext_vector_type(4))) float floatx4;

// fp32 -> bf16 round-to-nearest-even
__device__ __forceinline__ unsigned short f2bf(float f) {
    unsigned u = __float_as_uint(f);
    u += 0x7fffu + ((u >> 16) & 1u);
    return (unsigned short)(u >> 16);
}

// async global->LDS, 16B per lane; LDS dest = wave-uniform base + lane*16
__device__ __forceinline__ void gl_lds16(const void* g, void* l) {
    __builtin_amdgcn_global_load_lds((__attribute__((address_space(1))) void*)g,
                                     (__attribute__((address_space(3))) void*)l,
                                     16, 0, 0);
}

// ---------------------------------------------------------------------------
// Embed: h_bf[t,b,:] = bf16(token_emb[tokens[t,b],:] + pos_emb[t,:])
// ---------------------------------------------------------------------------
__global__ __launch_bounds__(256) void embed_kernel(
    const int* __restrict__ tokens, const float* __restrict__ temb,
    const float* __restrict__ pemb, unsigned short* __restrict__ hb)
{
    const int idx = blockIdx.x * 256 + threadIdx.x;      // 0 .. T*B*H/4-1
    const int h4 = idx & (H_ / 4 - 1);
    const int tb = idx >> 6;
    const int b  = tb & (B_ - 1);
    const int t  = tb >> 3;
    const int tok = tokens[t * B_ + b];
    const float4 e = *(const float4*)&temb[(size_t)tok * H_ + h4 * 4];
    const float4 p = *(const float4*)&pemb[(size_t)t * H_ + h4 * 4];
    ushort4 r;
    r.x = f2bf(e.x + p.x); r.y = f2bf(e.y + p.y);
    r.z = f2bf(e.z + p.z); r.w = f2bf(e.w + p.w);
    *(ushort4*)&hb[(size_t)idx * 4] = r;
}

// ---------------------------------------------------------------------------
// LDS-staged leaky scan + spike (bf16 spike output; 0/1 exact in bf16).
// One block per batch b, 256 threads = 256 h chains, double-buffered chunks.
// ---------------------------------------------------------------------------
__global__ __launch_bounds__(256) void scan_spike_lds(
    const float* __restrict__ cur, const float* __restrict__ beta_l,
    unsigned short* __restrict__ spk)
{
    __shared__ float buf[2][32][256];                     // 64 KiB
    const int b = blockIdx.x;
    const int tid = threadIdx.x;
    const float bt = beta_l[tid];
    const float* base = cur + (size_t)b * H_;
    unsigned short* qb = spk + (size_t)b * H_ + tid;
    constexpr int CH = 32;
    constexpr int NC = T_ / CH;                           // 16
    constexpr size_t TS = (size_t)B_ * H_;                // 2048

    float4 regs[8];
    #pragma unroll
    for (int i = 0; i < 8; ++i) {
        const int fi = tid + 256 * i, r = fi >> 6, x = fi & 63;
        regs[i] = *(const float4*)&base[(size_t)r * TS + x * 4];
    }
    #pragma unroll
    for (int i = 0; i < 8; ++i) {
        const int fi = tid + 256 * i, r = fi >> 6, x = fi & 63;
        *(float4*)&buf[0][r][x * 4] = regs[i];
    }

    float mem = 0.0f;
    for (int c = 0; c < NC; ++c) {
        __syncthreads();
        if (c + 1 < NC) {
            #pragma unroll
            for (int i = 0; i < 8; ++i) {
                const int fi = tid + 256 * i, r = fi >> 6, x = fi & 63;
                regs[i] = *(const float4*)&base[(size_t)((c + 1) * CH + r) * TS + x * 4];
            }
        }
        const int p = c & 1;
        #pragma unroll
        for (int tt = 0; tt < CH; ++tt) {
            mem = fmaf(bt, mem, buf[p][tt][tid]);
            qb[(size_t)(c * CH + tt) * TS] = (mem > 1.0f) ? (unsigned short)0x3F80u
                                                          : (unsigned short)0u;
        }
        if (c + 1 < NC) {
            #pragma unroll
            for (int i = 0; i < 8; ++i) {
                const int fi = tid + 256 * i, r = fi >> 6, x = fi & 63;
                *(float4*)&buf[(c + 1) & 1][r][x * 4] = regs[i];
            }
        }
    }
}

// ---------------------------------------------------------------------------
// Small weight transpose+cast: 6x [256][256] fp32 (k-major) -> [256][256] bf16
// (n-major). z in [0,6): 0..2 = Wq layers, 3..5 = Wfc layers.
// ---------------------------------------------------------------------------
__global__ __launch_bounds__(256) void transpose_small_kernel(
    const float* __restrict__ Wq, const float* __restrict__ Wfc,
    unsigned short* __restrict__ WT)
{
    __shared__ float t[64][65];
    const int z = blockIdx.z;
    const float* src = (z < 3) ? Wq + (size_t)z * H_ * H_
                               : Wfc + (size_t)(z - 3) * H_ * H_;
    unsigned short* dst = WT + (size_t)z * H_ * H_;
    const int n0 = blockIdx.x * 64, k0 = blockIdx.y * 64;
    const int x = threadIdx.x & 63, y = threadIdx.x >> 6;
    #pragma unroll
    for (int i = 0; i < 16; ++i)
        t[y + 4 * i][x] = src[(size_t)(k0 + y + 4 * i) * H_ + n0 + x];
    __syncthreads();
    #pragma unroll
    for (int i = 0; i < 16; ++i)
        dst[(size_t)(n0 + y + 4 * i) * H_ + k0 + x] = f2bf(t[x][y + 4 * i]);
}

// ---------------------------------------------------------------------------
// Wout [K=256][V] fp32 -> WoutT [V][K=256] bf16
// ---------------------------------------------------------------------------
__global__ __launch_bounds__(256) void transpose_wout_kernel(
    const float* __restrict__ W, unsigned short* __restrict__ Wt)
{
    __shared__ float t[64][65];
    const int n0 = blockIdx.x * 64;
    const int k0 = blockIdx.y * 64;
    const int x = threadIdx.x & 63, y = threadIdx.x >> 6;
    #pragma unroll
    for (int i = 0; i < 16; ++i)
        t[y + 4 * i][x] = W[(size_t)(k0 + y + 4 * i) * V_ + n0 + x];
    __syncthreads();
    #pragma unroll
    for (int i = 0; i < 16; ++i)
        Wt[(size_t)(n0 + y + 4 * i) * H_ + k0 + x] = f2bf(t[x][y + 4 * i]);
}

// ===========================================================================
// XOR-swizzled LDS staging scheme (shared by both MFMA GEMMs):
//   chunk = 16 B = 8 bf16 = one k-octet. Row of a BK=64 tile = 8 octets.
//   Slot for (row, oct):  s = row*8 + (oct ^ (row & 7)),  LDS byte addr s*16.
//   - global_load_lds: slots [base, base+64) <-> 8 rows x 8 permuted octets
//     = 8 x 128 B fully-coalesced line reads; LDS dest = base+lane*16 (legal).
//   - fragment ds_read_b128: 16 lanes (rows r..r+15) hit banks
//     4*((oct)^(r&7))+j -> permutation over all 32 banks, 2-way max (free).
// ===========================================================================

// ---------------------------------------------------------------------------
// Final projection: C[M,V] = A[M,256]bf16 @ WoutT[V,256]^T + bias, fp32 out.
// 128x128 tile, BK=64 (4 K-iters), 4 waves 2x2, 64x64 per wave.
// ---------------------------------------------------------------------------
__global__ __launch_bounds__(256) void gemm_mfma_out(
    const unsigned short* __restrict__ A,    // [M][256]
    const unsigned short* __restrict__ Bt,   // [V][256]
    const float* __restrict__ bias,          // [V]
    float* __restrict__ C)
{
    constexpr int K = H_, N = V_;
    __shared__ __align__(16) short lA[1024][8];   // 16 KiB (128 rows x 8 octets)
    __shared__ __align__(16) short lB[1024][8];   // 16 KiB

    const int tid = threadIdx.x;
    const int lane = tid & 63, wave = tid >> 6;
    const int wm = wave >> 1, wn = wave & 1;
    const int l15 = lane & 15, quad = lane >> 4;
    const int m0 = blockIdx.x * 128;              // x fast -> B-tile L2 reuse
    const int n0 = blockIdx.y * 128;

    floatx4 acc[4][4] = {};

    for (int k0 = 0; k0 < K; k0 += 64) {
        #pragma unroll
        for (int j = 0; j < 4; ++j) {
            const int base = (wave * 4 + j) * 64;
            const int s = base + lane;
            const int row = s >> 3;
            const int oct = (s & 7) ^ (row & 7);
            gl_lds16(A  + (size_t)(m0 + row) * K + k0 + oct * 8, &lA[base][0]);
            gl_lds16(Bt + (size_t)(n0 + row) * K + k0 + oct * 8, &lB[base][0]);
        }
        __syncthreads();

        #pragma unroll
        for (int t = 0; t < 2; ++t) {
            short8 af[4], bf[4];
            #pragma unroll
            for (int f = 0; f < 4; ++f) {
                const int ra = wm * 64 + f * 16 + l15;
                const int rb = wn * 64 + f * 16 + l15;
                af[f] = *(const short8*)&lA[ra * 8 + ((4 * t + quad) ^ (ra & 7))][0];
                bf[f] = *(const short8*)&lB[rb * 8 + ((4 * t + quad) ^ (rb & 7))][0];
            }
            #pragma unroll
            for (int i = 0; i < 4; ++i)
                #pragma unroll
                for (int j2 = 0; j2 < 4; ++j2)
                    acc[i][j2] = __builtin_amdgcn_mfma_f32_16x16x32_bf16(
                        af[i], bf[j2], acc[i][j2], 0, 0, 0);
        }
        __syncthreads();
    }

    // D layout: col = lane&15, row = quad*4 + reg (m89/m91-verified)
    #pragma unroll
    for (int j2 = 0; j2 < 4; ++j2) {
        const int col = n0 + wn * 64 + j2 * 16 + l15;
        const float bv = bias[col];
        #pragma unroll
        for (int i = 0; i < 4; ++i) {
            const int rbase = m0 + wm * 64 + i * 16 + quad * 4;
            #pragma unroll
            for (int r = 0; r < 4; ++r)
                C[(size_t)(rbase + r) * N + col] = acc[i][j2][r] + bv;
        }
    }
}

// ---------------------------------------------------------------------------
// Layer GEMM: [M,256] = A[M,256]bf16 @ Bt[256,256]^T + bias, optional ReLU,
// output fp32 (for scan) or bf16 (activations). 128x64 tile, BK=64, 4 waves
// 2x2 over (64m x 32n).
// ---------------------------------------------------------------------------
template <int RELU, int OUT_BF16>
__global__ __launch_bounds__(256) void gemm_mfma_layer(
    const unsigned short* __restrict__ A,    // [M][256]
    const unsigned short* __restrict__ Bt,   // [256][256]
    const float* __restrict__ bias,          // [256]
    float* __restrict__ Cf, unsigned short* __restrict__ Cb)
{
    constexpr int K = H_, N = H_;
    __shared__ __align__(16) short lA[1024][8];   // 128 rows
    __shared__ __align__(16) short lB[512][8];    // 64 rows

    const int tid = threadIdx.x;
    const int lane = tid & 63, wave = tid >> 6;
    const int wm = wave >> 1, wn = wave & 1;
    const int l15 = lane & 15, quad = lane >> 4;
    const int m0 = blockIdx.x * 128;
    const int n0 = blockIdx.y * 64;

    floatx4 acc[4][2] = {};

    for (int k0 = 0; k0 < K; k0 += 64) {
        #pragma unroll
        for (int j = 0; j < 4; ++j) {
            const int base = (wave * 4 + j) * 64;
            const int s = base + lane;
            const int row = s >> 3;
            const int oct = (s & 7) ^ (row & 7);
            gl_lds16(A + (size_t)(m0 + row) * K + k0 + oct * 8, &lA[base][0]);
        }
        #pragma unroll
        for (int j = 0; j < 2; ++j) {
            const int base = (wave * 2 + j) * 64;
            const int s = base + lane;
            const int row = s >> 3;                     // 0..63
            const int oct = (s & 7) ^ (row & 7);
            gl_lds16(Bt + (size_t)(n0 + row) * K + k0 + oct * 8, &lB[base][0]);
        }
        __syncthreads();

        #pragma unroll
        for (int t = 0; t < 2; ++t) {
            short8 af[4], bf[2];
            #pragma unroll
            for (int f = 0; f < 4; ++f) {
                const int ra = wm * 64 + f * 16 + l15;
                af[f] = *(const short8*)&lA[ra * 8 + ((4 * t + quad) ^ (ra & 7))][0];
            }
            #pragma unroll
            for (int f = 0; f < 2; ++f) {
                const int rb = wn * 32 + f * 16 + l15;
                bf[f] = *(const short8*)&lB[rb * 8 + ((4 * t + quad) ^ (rb & 7))][0];
            }
            #pragma unroll
            for (int i = 0; i < 4; ++i)
                #pragma unroll
                for (int j2 = 0; j2 < 2; ++j2)
                    acc[i][j2] = __builtin_amdgcn_mfma_f32_16x16x32_bf16(
                        af[i], bf[j2], acc[i][j2], 0, 0, 0);
        }
        __syncthreads();
    }

    #pragma unroll
    for (int j2 = 0; j2 < 2; ++j2) {
        const int col = n0 + wn * 32 + j2 * 16 + l15;
        const float bv = bias[col];
        #pragma unroll
        for (int i = 0; i < 4; ++i) {
            const int rbase = m0 + wm * 64 + i * 16 + quad * 4;
            #pragma unroll
            for (int r = 0; r < 4; ++r) {
                float v = acc[i][j2][r] + bv;
                if (RELU) v = fmaxf(v, 0.0f);
                if (OUT_BF16)
                    Cb[(size_t)(rbase + r) * N + col] = f2bf(v);
                else
                    Cf[(size_t)(rbase + r) * N + col] = v;
            }
        }
    }
}

// ---------------------------------------------------------------------------
extern "C" void kernel_launch(void* const* d_in, const int* in_sizes, int n_in,
                              void* d_out, int out_size, void* d_ws, size_t ws_size,
                              hipStream_t stream)
{
    const int*   tokens = (const int*)  d_in[0];
    const float* temb   = (const float*)d_in[1];
    const float* pemb   = (const float*)d_in[2];
    const float* Wq     = (const float*)d_in[3];
    const float* bq     = (const float*)d_in[4];
    const float* beta   = (const float*)d_in[5];
    const float* Wfc    = (const float*)d_in[6];
    const float* bfc    = (const float*)d_in[7];
    const float* Wout   = (const float*)d_in[8];
    const float* bout   = (const float*)d_in[9];
    float* out = (float*)d_out;

    // Workspace layout (all 16B-aligned): h_bf 2MB | spk 2MB | WT 0.75MB |
    // WoutT 16MB | cur 4MB
    unsigned short* h_bf  = (unsigned short*)d_ws;
    unsigned short* spk   = h_bf + (size_t)M_ * H_;
    unsigned short* WT    = spk + (size_t)M_ * H_;          // 6 x [256][256]
    unsigned short* WoutT = WT + (size_t)2 * L_ * H_ * H_;
    float*          cur   = (float*)(WoutT + (size_t)V_ * H_);

    // Weight transposes (independent of activation pipeline)
    transpose_small_kernel<<<dim3(4, 4, 6), 256, 0, stream>>>(Wq, Wfc, WT);
    transpose_wout_kernel<<<dim3(V_ / 64, H_ / 64), 256, 0, stream>>>(Wout, WoutT);

    // 1) embed (bf16 activations)
    embed_kernel<<<(M_ * H_ / 4) / 256, 256, 0, stream>>>(tokens, temb, pemb, h_bf);

    // 2) layers: qproj (fp32 out for scan) -> scan/spike (bf16 out) -> fc (bf16)
    for (int l = 0; l < L_; ++l) {
        const unsigned short* WqT  = WT + (size_t)l * H_ * H_;
        const unsigned short* WfcT = WT + (size_t)(L_ + l) * H_ * H_;
        gemm_mfma_layer<0, 0><<<dim3(M_ / 128, H_ / 64), 256, 0, stream>>>(
            h_bf, WqT, bq + (size_t)l * H_, cur, nullptr);
        scan_spike_lds<<<B_, 256, 0, stream>>>(cur, beta + (size_t)l * H_, spk);
        gemm_mfma_layer<1, 1><<<dim3(M_ / 128, H_ / 64), 256, 0, stream>>>(
            spk, WfcT, bfc + (size_t)l * H_, nullptr, h_bf);
    }

    // 3) output projection: (4096 x 256) @ (256 x 32000) + bout
    gemm_mfma_out<<<dim3(M_ / 128, V_ / 128), 256, 0, stream>>>(
        h_bf, WoutT, bout, out);
}

// Round 4
// 738.202 us; speedup vs baseline: 1.8820x; 1.0184x over previous
//
#include <hip/hip_runtime.h>
#include <hip/hip_bf16.h>
#include <cstddef>

// Problem constants (fixed by the reference)
constexpr int T_ = 512;
constexpr int B_ = 8;
constexpr int H_ = 256;
constexpr int V_ = 32000;
constexpr int L_ = 3;
constexpr int M_ = T_ * B_;   // 4096 rows in all GEMMs

typedef __attribute__((ext_vector_type(8))) short short8;
typedef __attribute__((ext_vector_type(4))) float floatx4;

// fp32 -> bf16 round-to-nearest-even
__device__ __forceinline__ unsigned short f2bf(float f) {
    unsigned u = __float_as_uint(f);
    u += 0x7fffu + ((u >> 16) & 1u);
    return (unsigned short)(u >> 16);
}

// async global->LDS, 16B per lane; LDS dest = wave-uniform base + lane*16
__device__ __forceinline__ void gl_lds16(const void* g, void* l) {
    __builtin_amdgcn_global_load_lds((__attribute__((address_space(1))) void*)g,
                                     (__attribute__((address_space(3))) void*)l,
                                     16, 0, 0);
}

// ---------------------------------------------------------------------------
// Embed: h_bf[t,b,:] = bf16(token_emb[tokens[t,b],:] + pos_emb[t,:])
// ---------------------------------------------------------------------------
__global__ __launch_bounds__(256) void embed_kernel(
    const int* __restrict__ tokens, const float* __restrict__ temb,
    const float* __restrict__ pemb, unsigned short* __restrict__ hb)
{
    const int idx = blockIdx.x * 256 + threadIdx.x;      // 0 .. T*B*H/4-1
    const int h4 = idx & (H_ / 4 - 1);
    const int tb = idx >> 6;
    const int b  = tb & (B_ - 1);
    const int t  = tb >> 3;
    const int tok = tokens[t * B_ + b];
    const float4 e = *(const float4*)&temb[(size_t)tok * H_ + h4 * 4];
    const float4 p = *(const float4*)&pemb[(size_t)t * H_ + h4 * 4];
    ushort4 r;
    r.x = f2bf(e.x + p.x); r.y = f2bf(e.y + p.y);
    r.z = f2bf(e.z + p.z); r.w = f2bf(e.w + p.w);
    *(ushort4*)&hb[(size_t)idx * 4] = r;
}

// ===========================================================================
// Parallel chunked leaky scan. mem[t] = beta*mem[t-1] + cur[t] is linear ->
// chunk decomposition: local scan (carry 0) per 32-step chunk, then
// mem[t] = local[t] + beta^(tt+1) * carry_chunk, carry via beta^32 recurrence
// over chunk-end values. Spike margin is ~0.9 (mem sigma ~0.09 vs thresh 1.0)
// so the ~1e-7 rounding difference vs the sequential order cannot flip spikes.
// ===========================================================================
constexpr int CH_ = 32;
constexpr int NT_ = T_ / CH_;          // 16 chunks
constexpr int TS_ = B_ * H_;           // 2048: t-stride in [T][B][H]

__global__ __launch_bounds__(256) void scan_local_kernel(
    const float* __restrict__ cur, const float* __restrict__ beta_l,
    float* __restrict__ mloc)
{
    const int c = blockIdx.x, b = blockIdx.y, h = threadIdx.x;
    const float bt = beta_l[h];
    const size_t off = ((size_t)(c * CH_) * B_ + b) * H_ + h;
    const float* p = cur + off;
    float* q = mloc + off;
    float mem = 0.0f;
    #pragma unroll
    for (int tt = 0; tt < CH_; ++tt) {
        mem = fmaf(bt, mem, p[(size_t)tt * TS_]);
        q[(size_t)tt * TS_] = mem;
    }
}

__global__ __launch_bounds__(256) void scan_apply_kernel(
    const float* __restrict__ mloc, const float* __restrict__ beta_l,
    unsigned short* __restrict__ spk)
{
    const int c = blockIdx.x, b = blockIdx.y, h = threadIdx.x;
    const float bt = beta_l[h];
    float b32 = bt;
    #pragma unroll
    for (int i = 0; i < 5; ++i) b32 *= b32;        // beta^32 (CH_=32)
    // carry = true mem at end of chunk c-1 (0 for chunk 0)
    float carry = 0.0f;
    for (int j = 0; j < c; ++j)
        carry = fmaf(b32, carry,
                     mloc[((size_t)(j * CH_ + CH_ - 1) * B_ + b) * H_ + h]);
    const size_t off = ((size_t)(c * CH_) * B_ + b) * H_ + h;
    const float* p = mloc + off;
    unsigned short* q = spk + off;
    float pw = bt;                                  // beta^(tt+1)
    #pragma unroll
    for (int tt = 0; tt < CH_; ++tt) {
        const float mem = fmaf(pw, carry, p[(size_t)tt * TS_]);
        pw *= bt;
        q[(size_t)tt * TS_] = (mem > 1.0f) ? (unsigned short)0x3F80u
                                           : (unsigned short)0u;
    }
}

// ---------------------------------------------------------------------------
// Small weight transpose+cast: 6x [256][256] fp32 (k-major) -> [256][256] bf16
// (n-major). z in [0,6): 0..2 = Wq layers, 3..5 = Wfc layers.
// ---------------------------------------------------------------------------
__global__ __launch_bounds__(256) void transpose_small_kernel(
    const float* __restrict__ Wq, const float* __restrict__ Wfc,
    unsigned short* __restrict__ WT)
{
    __shared__ float t[64][65];
    const int z = blockIdx.z;
    const float* src = (z < 3) ? Wq + (size_t)z * H_ * H_
                               : Wfc + (size_t)(z - 3) * H_ * H_;
    unsigned short* dst = WT + (size_t)z * H_ * H_;
    const int n0 = blockIdx.x * 64, k0 = blockIdx.y * 64;
    const int x = threadIdx.x & 63, y = threadIdx.x >> 6;
    #pragma unroll
    for (int i = 0; i < 16; ++i)
        t[y + 4 * i][x] = src[(size_t)(k0 + y + 4 * i) * H_ + n0 + x];
    __syncthreads();
    #pragma unroll
    for (int i = 0; i < 16; ++i)
        dst[(size_t)(n0 + y + 4 * i) * H_ + k0 + x] = f2bf(t[x][y + 4 * i]);
}

// ---------------------------------------------------------------------------
// Wout [K=256][V] fp32 -> WoutT [V][K=256] bf16
// ---------------------------------------------------------------------------
__global__ __launch_bounds__(256) void transpose_wout_kernel(
    const float* __restrict__ W, unsigned short* __restrict__ Wt)
{
    __shared__ float t[64][65];
    const int n0 = blockIdx.x * 64;
    const int k0 = blockIdx.y * 64;
    const int x = threadIdx.x & 63, y = threadIdx.x >> 6;
    #pragma unroll
    for (int i = 0; i < 16; ++i)
        t[y + 4 * i][x] = W[(size_t)(k0 + y + 4 * i) * V_ + n0 + x];
    __syncthreads();
    #pragma unroll
    for (int i = 0; i < 16; ++i)
        Wt[(size_t)(n0 + y + 4 * i) * H_ + k0 + x] = f2bf(t[x][y + 4 * i]);
}

// ===========================================================================
// XOR-swizzled LDS staging scheme (shared by both MFMA GEMMs):
//   chunk = 16 B = 8 bf16 = one k-octet. Row of a BK=64 tile = 8 octets.
//   Slot for (row, oct):  s = row*8 + (oct ^ (row & 7)),  LDS byte addr s*16.
//   - global_load_lds: slots [base, base+64) <-> 8 rows x 8 permuted octets
//     = 8 x 128 B fully-coalesced line reads; LDS dest = base+lane*16 (legal).
//   - fragment ds_read_b128: 16 lanes (rows r..r+15) hit banks
//     4*((oct)^(r&7))+j -> permutation over all 32 banks, 2-way max (free).
// ===========================================================================

// ---------------------------------------------------------------------------
// Final projection: C[M,V] = A[M,256]bf16 @ WoutT[V,256]^T + bias, fp32 out.
// 128x128 tile, BK=64 (4 K-iters), 4 waves 2x2, 64x64 per wave.
// ---------------------------------------------------------------------------
__global__ __launch_bounds__(256) void gemm_mfma_out(
    const unsigned short* __restrict__ A,    // [M][256]
    const unsigned short* __restrict__ Bt,   // [V][256]
    const float* __restrict__ bias,          // [V]
    float* __restrict__ C)
{
    constexpr int K = H_, N = V_;
    __shared__ __align__(16) short lA[1024][8];   // 16 KiB (128 rows x 8 octets)
    __shared__ __align__(16) short lB[1024][8];   // 16 KiB

    const int tid = threadIdx.x;
    const int lane = tid & 63, wave = tid >> 6;
    const int wm = wave >> 1, wn = wave & 1;
    const int l15 = lane & 15, quad = lane >> 4;
    const int m0 = blockIdx.x * 128;              // x fast -> B-tile L2 reuse
    const int n0 = blockIdx.y * 128;

    floatx4 acc[4][4] = {};

    for (int k0 = 0; k0 < K; k0 += 64) {
        #pragma unroll
        for (int j = 0; j < 4; ++j) {
            const int base = (wave * 4 + j) * 64;
            const int s = base + lane;
            const int row = s >> 3;
            const int oct = (s & 7) ^ (row & 7);
            gl_lds16(A  + (size_t)(m0 + row) * K + k0 + oct * 8, &lA[base][0]);
            gl_lds16(Bt + (size_t)(n0 + row) * K + k0 + oct * 8, &lB[base][0]);
        }
        __syncthreads();

        #pragma unroll
        for (int t = 0; t < 2; ++t) {
            short8 af[4], bf[4];
            #pragma unroll
            for (int f = 0; f < 4; ++f) {
                const int ra = wm * 64 + f * 16 + l15;
                const int rb = wn * 64 + f * 16 + l15;
                af[f] = *(const short8*)&lA[ra * 8 + ((4 * t + quad) ^ (ra & 7))][0];
                bf[f] = *(const short8*)&lB[rb * 8 + ((4 * t + quad) ^ (rb & 7))][0];
            }
            #pragma unroll
            for (int i = 0; i < 4; ++i)
                #pragma unroll
                for (int j2 = 0; j2 < 4; ++j2)
                    acc[i][j2] = __builtin_amdgcn_mfma_f32_16x16x32_bf16(
                        af[i], bf[j2], acc[i][j2], 0, 0, 0);
        }
        __syncthreads();
    }

    // D layout: col = lane&15, row = quad*4 + reg (m89/m91-verified)
    #pragma unroll
    for (int j2 = 0; j2 < 4; ++j2) {
        const int col = n0 + wn * 64 + j2 * 16 + l15;
        const float bv = bias[col];
        #pragma unroll
        for (int i = 0; i < 4; ++i) {
            const int rbase = m0 + wm * 64 + i * 16 + quad * 4;
            #pragma unroll
            for (int r = 0; r < 4; ++r)
                C[(size_t)(rbase + r) * N + col] = acc[i][j2][r] + bv;
        }
    }
}

// ---------------------------------------------------------------------------
// Layer GEMM: [M,256] = A[M,256]bf16 @ Bt[256,256]^T + bias, optional ReLU,
// output fp32 (for scan) or bf16 (activations). 128x64 tile, BK=64, 4 waves
// 2x2 over (64m x 32n).
// ---------------------------------------------------------------------------
template <int RELU, int OUT_BF16>
__global__ __launch_bounds__(256) void gemm_mfma_layer(
    const unsigned short* __restrict__ A,    // [M][256]
    const unsigned short* __restrict__ Bt,   // [256][256]
    const float* __restrict__ bias,          // [256]
    float* __restrict__ Cf, unsigned short* __restrict__ Cb)
{
    constexpr int K = H_, N = H_;
    __shared__ __align__(16) short lA[1024][8];   // 128 rows
    __shared__ __align__(16) short lB[512][8];    // 64 rows

    const int tid = threadIdx.x;
    const int lane = tid & 63, wave = tid >> 6;
    const int wm = wave >> 1, wn = wave & 1;
    const int l15 = lane & 15, quad = lane >> 4;
    const int m0 = blockIdx.x * 128;
    const int n0 = blockIdx.y * 64;

    floatx4 acc[4][2] = {};

    for (int k0 = 0; k0 < K; k0 += 64) {
        #pragma unroll
        for (int j = 0; j < 4; ++j) {
            const int base = (wave * 4 + j) * 64;
            const int s = base + lane;
            const int row = s >> 3;
            const int oct = (s & 7) ^ (row & 7);
            gl_lds16(A + (size_t)(m0 + row) * K + k0 + oct * 8, &lA[base][0]);
        }
        #pragma unroll
        for (int j = 0; j < 2; ++j) {
            const int base = (wave * 2 + j) * 64;
            const int s = base + lane;
            const int row = s >> 3;                     // 0..63
            const int oct = (s & 7) ^ (row & 7);
            gl_lds16(Bt + (size_t)(n0 + row) * K + k0 + oct * 8, &lB[base][0]);
        }
        __syncthreads();

        #pragma unroll
        for (int t = 0; t < 2; ++t) {
            short8 af[4], bf[2];
            #pragma unroll
            for (int f = 0; f < 4; ++f) {
                const int ra = wm * 64 + f * 16 + l15;
                af[f] = *(const short8*)&lA[ra * 8 + ((4 * t + quad) ^ (ra & 7))][0];
            }
            #pragma unroll
            for (int f = 0; f < 2; ++f) {
                const int rb = wn * 32 + f * 16 + l15;
                bf[f] = *(const short8*)&lB[rb * 8 + ((4 * t + quad) ^ (rb & 7))][0];
            }
            #pragma unroll
            for (int i = 0; i < 4; ++i)
                #pragma unroll
                for (int j2 = 0; j2 < 2; ++j2)
                    acc[i][j2] = __builtin_amdgcn_mfma_f32_16x16x32_bf16(
                        af[i], bf[j2], acc[i][j2], 0, 0, 0);
        }
        __syncthreads();
    }

    #pragma unroll
    for (int j2 = 0; j2 < 2; ++j2) {
        const int col = n0 + wn * 32 + j2 * 16 + l15;
        const float bv = bias[col];
        #pragma unroll
        for (int i = 0; i < 4; ++i) {
            const int rbase = m0 + wm * 64 + i * 16 + quad * 4;
            #pragma unroll
            for (int r = 0; r < 4; ++r) {
                float v = acc[i][j2][r] + bv;
                if (RELU) v = fmaxf(v, 0.0f);
                if (OUT_BF16)
                    Cb[(size_t)(rbase + r) * N + col] = f2bf(v);
                else
                    Cf[(size_t)(rbase + r) * N + col] = v;
            }
        }
    }
}

// ---------------------------------------------------------------------------
extern "C" void kernel_launch(void* const* d_in, const int* in_sizes, int n_in,
                              void* d_out, int out_size, void* d_ws, size_t ws_size,
                              hipStream_t stream)
{
    const int*   tokens = (const int*)  d_in[0];
    const float* temb   = (const float*)d_in[1];
    const float* pemb   = (const float*)d_in[2];
    const float* Wq     = (const float*)d_in[3];
    const float* bq     = (const float*)d_in[4];
    const float* beta   = (const float*)d_in[5];
    const float* Wfc    = (const float*)d_in[6];
    const float* bfc    = (const float*)d_in[7];
    const float* Wout   = (const float*)d_in[8];
    const float* bout   = (const float*)d_in[9];
    float* out = (float*)d_out;

    // Workspace layout (all 16B-aligned): h_bf 2MB | spk 2MB | WT 0.75MB |
    // WoutT 16MB | cur 4MB | mloc 4MB
    unsigned short* h_bf  = (unsigned short*)d_ws;
    unsigned short* spk   = h_bf + (size_t)M_ * H_;
    unsigned short* WT    = spk + (size_t)M_ * H_;          // 6 x [256][256]
    unsigned short* WoutT = WT + (size_t)2 * L_ * H_ * H_;
    float*          cur   = (float*)(WoutT + (size_t)V_ * H_);
    float*          mloc  = cur + (size_t)M_ * H_;

    // Weight transposes (independent of activation pipeline)
    transpose_small_kernel<<<dim3(4, 4, 6), 256, 0, stream>>>(Wq, Wfc, WT);
    transpose_wout_kernel<<<dim3(V_ / 64, H_ / 64), 256, 0, stream>>>(Wout, WoutT);

    // 1) embed (bf16 activations)
    embed_kernel<<<(M_ * H_ / 4) / 256, 256, 0, stream>>>(tokens, temb, pemb, h_bf);

    // 2) layers: qproj (fp32 out) -> parallel scan/spike (bf16 out) -> fc (bf16)
    for (int l = 0; l < L_; ++l) {
        const unsigned short* WqT  = WT + (size_t)l * H_ * H_;
        const unsigned short* WfcT = WT + (size_t)(L_ + l) * H_ * H_;
        gemm_mfma_layer<0, 0><<<dim3(M_ / 128, H_ / 64), 256, 0, stream>>>(
            h_bf, WqT, bq + (size_t)l * H_, cur, nullptr);
        scan_local_kernel<<<dim3(NT_, B_), 256, 0, stream>>>(
            cur, beta + (size_t)l * H_, mloc);
        scan_apply_kernel<<<dim3(NT_, B_), 256, 0, stream>>>(
            mloc, beta + (size_t)l * H_, spk);
        gemm_mfma_layer<1, 1><<<dim3(M_ / 128, H_ / 64), 256, 0, stream>>>(
            spk, WfcT, bfc + (size_t)l * H_, nullptr, h_bf);
    }

    // 3) output projection: (4096 x 256) @ (256 x 32000) + bout
    gemm_mfma_out<<<dim3(M_ / 128, V_ / 128), 256, 0, stream>>>(
        h_bf, WoutT, bout, out);
}

// Round 5
// 714.209 us; speedup vs baseline: 1.9453x; 1.0336x over previous
//
#include <hip/hip_runtime.h>
#include <hip/hip_bf16.h>
#include <cstddef>

// Problem constants (fixed by the reference)
constexpr int T_ = 512;
constexpr int B_ = 8;
constexpr int H_ = 256;
constexpr int V_ = 32000;
constexpr int L_ = 3;
constexpr int M_ = T_ * B_;   // 4096 rows in all GEMMs

typedef __attribute__((ext_vector_type(8))) short short8;
typedef __attribute__((ext_vector_type(4))) float floatx4;

// fp32 -> bf16 round-to-nearest-even
__device__ __forceinline__ unsigned short f2bf(float f) {
    unsigned u = __float_as_uint(f);
    u += 0x7fffu + ((u >> 16) & 1u);
    return (unsigned short)(u >> 16);
}

// async global->LDS, 16B per lane; LDS dest = wave-uniform base + lane*16
__device__ __forceinline__ void gl_lds16(const void* g, void* l) {
    __builtin_amdgcn_global_load_lds((__attribute__((address_space(1))) void*)g,
                                     (__attribute__((address_space(3))) void*)l,
                                     16, 0, 0);
}

// ---------------------------------------------------------------------------
// Embed: h_bf[t,b,:] = bf16(token_emb[tokens[t,b],:] + pos_emb[t,:])
// ---------------------------------------------------------------------------
__global__ __launch_bounds__(256) void embed_kernel(
    const int* __restrict__ tokens, const float* __restrict__ temb,
    const float* __restrict__ pemb, unsigned short* __restrict__ hb)
{
    const int idx = blockIdx.x * 256 + threadIdx.x;      // 0 .. T*B*H/4-1
    const int h4 = idx & (H_ / 4 - 1);
    const int tb = idx >> 6;
    const int b  = tb & (B_ - 1);
    const int t  = tb >> 3;
    const int tok = tokens[t * B_ + b];
    const float4 e = *(const float4*)&temb[(size_t)tok * H_ + h4 * 4];
    const float4 p = *(const float4*)&pemb[(size_t)t * H_ + h4 * 4];
    ushort4 r;
    r.x = f2bf(e.x + p.x); r.y = f2bf(e.y + p.y);
    r.z = f2bf(e.z + p.z); r.w = f2bf(e.w + p.w);
    *(ushort4*)&hb[(size_t)idx * 4] = r;
}

// ===========================================================================
// Parallel chunked leaky scan (linear recurrence; chunk-local + carry apply).
// Spike margin ~0.9 vs the ~1e-7 reordering delta -> no spike flips.
// ===========================================================================
constexpr int CH_ = 32;
constexpr int NT_ = T_ / CH_;          // 16 chunks
constexpr int TS_ = B_ * H_;           // 2048: t-stride in [T][B][H]

__global__ __launch_bounds__(256) void scan_local_kernel(
    const float* __restrict__ cur, const float* __restrict__ beta_l,
    float* __restrict__ mloc)
{
    const int c = blockIdx.x, b = blockIdx.y, h = threadIdx.x;
    const float bt = beta_l[h];
    const size_t off = ((size_t)(c * CH_) * B_ + b) * H_ + h;
    const float* p = cur + off;
    float* q = mloc + off;
    float mem = 0.0f;
    #pragma unroll
    for (int tt = 0; tt < CH_; ++tt) {
        mem = fmaf(bt, mem, p[(size_t)tt * TS_]);
        q[(size_t)tt * TS_] = mem;
    }
}

__global__ __launch_bounds__(256) void scan_apply_kernel(
    const float* __restrict__ mloc, const float* __restrict__ beta_l,
    unsigned short* __restrict__ spk)
{
    const int c = blockIdx.x, b = blockIdx.y, h = threadIdx.x;
    const float bt = beta_l[h];
    float b32 = bt;
    #pragma unroll
    for (int i = 0; i < 5; ++i) b32 *= b32;        // beta^32 (CH_=32)
    float carry = 0.0f;
    for (int j = 0; j < c; ++j)
        carry = fmaf(b32, carry,
                     mloc[((size_t)(j * CH_ + CH_ - 1) * B_ + b) * H_ + h]);
    const size_t off = ((size_t)(c * CH_) * B_ + b) * H_ + h;
    const float* p = mloc + off;
    unsigned short* q = spk + off;
    float pw = bt;                                  // beta^(tt+1)
    #pragma unroll
    for (int tt = 0; tt < CH_; ++tt) {
        const float mem = fmaf(pw, carry, p[(size_t)tt * TS_]);
        pw *= bt;
        q[(size_t)tt * TS_] = (mem > 1.0f) ? (unsigned short)0x3F80u
                                           : (unsigned short)0u;
    }
}

// ---------------------------------------------------------------------------
// Small weight transpose+cast: 6x [256][256] fp32 (k-major) -> [256][256] bf16
// ---------------------------------------------------------------------------
__global__ __launch_bounds__(256) void transpose_small_kernel(
    const float* __restrict__ Wq, const float* __restrict__ Wfc,
    unsigned short* __restrict__ WT)
{
    __shared__ float t[64][65];
    const int z = blockIdx.z;
    const float* src = (z < 3) ? Wq + (size_t)z * H_ * H_
                               : Wfc + (size_t)(z - 3) * H_ * H_;
    unsigned short* dst = WT + (size_t)z * H_ * H_;
    const int n0 = blockIdx.x * 64, k0 = blockIdx.y * 64;
    const int x = threadIdx.x & 63, y = threadIdx.x >> 6;
    #pragma unroll
    for (int i = 0; i < 16; ++i)
        t[y + 4 * i][x] = src[(size_t)(k0 + y + 4 * i) * H_ + n0 + x];
    __syncthreads();
    #pragma unroll
    for (int i = 0; i < 16; ++i)
        dst[(size_t)(n0 + y + 4 * i) * H_ + k0 + x] = f2bf(t[x][y + 4 * i]);
}

// ---------------------------------------------------------------------------
// Wout [K=256][V] fp32 -> WoutT [V][K=256] bf16
// ---------------------------------------------------------------------------
__global__ __launch_bounds__(256) void transpose_wout_kernel(
    const float* __restrict__ W, unsigned short* __restrict__ Wt)
{
    __shared__ float t[64][65];
    const int n0 = blockIdx.x * 64;
    const int k0 = blockIdx.y * 64;
    const int x = threadIdx.x & 63, y = threadIdx.x >> 6;
    #pragma unroll
    for (int i = 0; i < 16; ++i)
        t[y + 4 * i][x] = W[(size_t)(k0 + y + 4 * i) * V_ + n0 + x];
    __syncthreads();
    #pragma unroll
    for (int i = 0; i < 16; ++i)
        Wt[(size_t)(n0 + y + 4 * i) * H_ + k0 + x] = f2bf(t[x][y + 4 * i]);
}

// ===========================================================================
// XOR-swizzled LDS staging scheme (all MFMA GEMMs):
//   chunk = 16 B = 8 bf16 = one k-octet. Row of a BK=64 tile = 8 octets.
//   Slot for (row, oct):  s = row*8 + (oct ^ (row & 7)),  LDS byte addr s*16.
//   global_load_lds groups of 64 slots = 8 rows x 8 permuted octets
//   = 8 x 128 B coalesced line reads; fragment ds_read_b128 spreads uniformly
//   over all 32 banks (2-way max aliasing = free per m136).
// ===========================================================================

// ---------------------------------------------------------------------------
// Final projection: C[M,V] = A[M,256]bf16 @ WoutT[V,256]^T + bias, fp32 out.
// Block-tile 256m x 128n (2 m-tiles share one B-tile): B-staging and barrier
// count per output halved vs 128x128. 4 waves 2x2 -> wave-tile 128m x 64n,
// acc 8x4 floatx4 = 128 VGPRs. LDS 48 KiB -> 2 blocks/CU (launch_bounds).
// Non-temporal C stores keep Wt/A in L2 (C is never re-read).
// ---------------------------------------------------------------------------
__global__ __launch_bounds__(256, 2) void gemm_mfma_out(
    const unsigned short* __restrict__ A,    // [M][256]
    const unsigned short* __restrict__ Bt,   // [V][256]
    const float* __restrict__ bias,          // [V]
    float* __restrict__ C)
{
    constexpr int K = H_, N = V_;
    __shared__ __align__(16) short lA[2048][8];   // 32 KiB: 256 rows x 8 octets
    __shared__ __align__(16) short lB[1024][8];   // 16 KiB: 128 rows

    const int tid = threadIdx.x;
    const int lane = tid & 63, wave = tid >> 6;
    const int wm = wave >> 1, wn = wave & 1;     // wave-tile: 128m x 64n
    const int l15 = lane & 15, quad = lane >> 4;
    const int m0 = blockIdx.x * 256;             // x = m (fast): 16 blocks/n-tile
    const int n0 = blockIdx.y * 128;

    floatx4 acc[8][4] = {};

    for (int k0 = 0; k0 < K; k0 += 64) {
        // stage A: 256 rows x 8 octets = 2048 slots, 8 chunk-groups of 64/wave-pass
        #pragma unroll
        for (int j = 0; j < 8; ++j) {
            const int base = (wave * 8 + j) * 64;
            const int s = base + lane;
            const int row = s >> 3;
            const int oct = (s & 7) ^ (row & 7);
            gl_lds16(A + (size_t)(m0 + row) * K + k0 + oct * 8, &lA[base][0]);
        }
        // stage B: 128 rows = 1024 slots
        #pragma unroll
        for (int j = 0; j < 4; ++j) {
            const int base = (wave * 4 + j) * 64;
            const int s = base + lane;
            const int row = s >> 3;
            const int oct = (s & 7) ^ (row & 7);
            gl_lds16(Bt + (size_t)(n0 + row) * K + k0 + oct * 8, &lB[base][0]);
        }
        __syncthreads();

        #pragma unroll
        for (int t = 0; t < 2; ++t) {
            short8 af[8], bf[4];
            #pragma unroll
            for (int f = 0; f < 8; ++f) {
                const int ra = wm * 128 + f * 16 + l15;
                af[f] = *(const short8*)&lA[ra * 8 + ((4 * t + quad) ^ (ra & 7))][0];
            }
            #pragma unroll
            for (int g = 0; g < 4; ++g) {
                const int rb = wn * 64 + g * 16 + l15;
                bf[g] = *(const short8*)&lB[rb * 8 + ((4 * t + quad) ^ (rb & 7))][0];
            }
            #pragma unroll
            for (int f = 0; f < 8; ++f)
                #pragma unroll
                for (int g = 0; g < 4; ++g)
                    acc[f][g] = __builtin_amdgcn_mfma_f32_16x16x32_bf16(
                        af[f], bf[g], acc[f][g], 0, 0, 0);
        }
        __syncthreads();
    }

    // Epilogue: D layout col=lane&15, row=quad*4+reg (m89/m91-verified).
    // Non-temporal stores: C stream is write-once.
    #pragma unroll
    for (int g = 0; g < 4; ++g) {
        const int col = n0 + wn * 64 + g * 16 + l15;
        const float bv = bias[col];
        #pragma unroll
        for (int f = 0; f < 8; ++f) {
            const int rbase = m0 + wm * 128 + f * 16 + quad * 4;
            #pragma unroll
            for (int r = 0; r < 4; ++r)
                __builtin_nontemporal_store(acc[f][g][r] + bv,
                                            &C[(size_t)(rbase + r) * N + col]);
        }
    }
}

// ---------------------------------------------------------------------------
// Layer GEMM: [M,256] = A[M,256]bf16 @ Bt[256,256]^T + bias, optional ReLU,
// output fp32 (for scan) or bf16 (activations). 128x64 tile, BK=64, 4 waves
// 2x2 over (64m x 32n). (Unchanged from R4 — passes, ~3 us each.)
// ---------------------------------------------------------------------------
template <int RELU, int OUT_BF16>
__global__ __launch_bounds__(256) void gemm_mfma_layer(
    const unsigned short* __restrict__ A,    // [M][256]
    const unsigned short* __restrict__ Bt,   // [256][256]
    const float* __restrict__ bias,          // [256]
    float* __restrict__ Cf, unsigned short* __restrict__ Cb)
{
    constexpr int K = H_, N = H_;
    __shared__ __align__(16) short lA[1024][8];   // 128 rows
    __shared__ __align__(16) short lB[512][8];    // 64 rows

    const int tid = threadIdx.x;
    const int lane = tid & 63, wave = tid >> 6;
    const int wm = wave >> 1, wn = wave & 1;
    const int l15 = lane & 15, quad = lane >> 4;
    const int m0 = blockIdx.x * 128;
    const int n0 = blockIdx.y * 64;

    floatx4 acc[4][2] = {};

    for (int k0 = 0; k0 < K; k0 += 64) {
        #pragma unroll
        for (int j = 0; j < 4; ++j) {
            const int base = (wave * 4 + j) * 64;
            const int s = base + lane;
            const int row = s >> 3;
            const int oct = (s & 7) ^ (row & 7);
            gl_lds16(A + (size_t)(m0 + row) * K + k0 + oct * 8, &lA[base][0]);
        }
        #pragma unroll
        for (int j = 0; j < 2; ++j) {
            const int base = (wave * 2 + j) * 64;
            const int s = base + lane;
            const int row = s >> 3;
            const int oct = (s & 7) ^ (row & 7);
            gl_lds16(Bt + (size_t)(n0 + row) * K + k0 + oct * 8, &lB[base][0]);
        }
        __syncthreads();

        #pragma unroll
        for (int t = 0; t < 2; ++t) {
            short8 af[4], bf[2];
            #pragma unroll
            for (int f = 0; f < 4; ++f) {
                const int ra = wm * 64 + f * 16 + l15;
                af[f] = *(const short8*)&lA[ra * 8 + ((4 * t + quad) ^ (ra & 7))][0];
            }
            #pragma unroll
            for (int f = 0; f < 2; ++f) {
                const int rb = wn * 32 + f * 16 + l15;
                bf[f] = *(const short8*)&lB[rb * 8 + ((4 * t + quad) ^ (rb & 7))][0];
            }
            #pragma unroll
            for (int i = 0; i < 4; ++i)
                #pragma unroll
                for (int j2 = 0; j2 < 2; ++j2)
                    acc[i][j2] = __builtin_amdgcn_mfma_f32_16x16x32_bf16(
                        af[i], bf[j2], acc[i][j2], 0, 0, 0);
        }
        __syncthreads();
    }

    #pragma unroll
    for (int j2 = 0; j2 < 2; ++j2) {
        const int col = n0 + wn * 32 + j2 * 16 + l15;
        const float bv = bias[col];
        #pragma unroll
        for (int i = 0; i < 4; ++i) {
            const int rbase = m0 + wm * 64 + i * 16 + quad * 4;
            #pragma unroll
            for (int r = 0; r < 4; ++r) {
                float v = acc[i][j2][r] + bv;
                if (RELU) v = fmaxf(v, 0.0f);
                if (OUT_BF16)
                    Cb[(size_t)(rbase + r) * N + col] = f2bf(v);
                else
                    Cf[(size_t)(rbase + r) * N + col] = v;
            }
        }
    }
}

// ---------------------------------------------------------------------------
extern "C" void kernel_launch(void* const* d_in, const int* in_sizes, int n_in,
                              void* d_out, int out_size, void* d_ws, size_t ws_size,
                              hipStream_t stream)
{
    const int*   tokens = (const int*)  d_in[0];
    const float* temb   = (const float*)d_in[1];
    const float* pemb   = (const float*)d_in[2];
    const float* Wq     = (const float*)d_in[3];
    const float* bq     = (const float*)d_in[4];
    const float* beta   = (const float*)d_in[5];
    const float* Wfc    = (const float*)d_in[6];
    const float* bfc    = (const float*)d_in[7];
    const float* Wout   = (const float*)d_in[8];
    const float* bout   = (const float*)d_in[9];
    float* out = (float*)d_out;

    // Workspace layout (all 16B-aligned): h_bf 2MB | spk 2MB | WT 0.75MB |
    // WoutT 16MB | cur 4MB | mloc 4MB
    unsigned short* h_bf  = (unsigned short*)d_ws;
    unsigned short* spk   = h_bf + (size_t)M_ * H_;
    unsigned short* WT    = spk + (size_t)M_ * H_;          // 6 x [256][256]
    unsigned short* WoutT = WT + (size_t)2 * L_ * H_ * H_;
    float*          cur   = (float*)(WoutT + (size_t)V_ * H_);
    float*          mloc  = cur + (size_t)M_ * H_;

    // Weight transposes (independent of activation pipeline)
    transpose_small_kernel<<<dim3(4, 4, 6), 256, 0, stream>>>(Wq, Wfc, WT);
    transpose_wout_kernel<<<dim3(V_ / 64, H_ / 64), 256, 0, stream>>>(Wout, WoutT);

    // 1) embed (bf16 activations)
    embed_kernel<<<(M_ * H_ / 4) / 256, 256, 0, stream>>>(tokens, temb, pemb, h_bf);

    // 2) layers: qproj (fp32 out) -> parallel scan/spike (bf16 out) -> fc (bf16)
    for (int l = 0; l < L_; ++l) {
        const unsigned short* WqT  = WT + (size_t)l * H_ * H_;
        const unsigned short* WfcT = WT + (size_t)(L_ + l) * H_ * H_;
        gemm_mfma_layer<0, 0><<<dim3(M_ / 128, H_ / 64), 256, 0, stream>>>(
            h_bf, WqT, bq + (size_t)l * H_, cur, nullptr);
        scan_local_kernel<<<dim3(NT_, B_), 256, 0, stream>>>(
            cur, beta + (size_t)l * H_, mloc);
        scan_apply_kernel<<<dim3(NT_, B_), 256, 0, stream>>>(
            mloc, beta + (size_t)l * H_, spk);
        gemm_mfma_layer<1, 1><<<dim3(M_ / 128, H_ / 64), 256, 0, stream>>>(
            spk, WfcT, bfc + (size_t)l * H_, nullptr, h_bf);
    }

    // 3) output projection: (4096 x 256) @ (256 x 32000) + bout
    gemm_mfma_out<<<dim3(M_ / 256, V_ / 128), 256, 0, stream>>>(
        h_bf, WoutT, bout, out);
}